// Round 4
// baseline (46278.217 us; speedup 1.0000x reference)
//
#include <hip/hip_runtime.h>
#include <hip/hip_cooperative_groups.h>
#include <math.h>

namespace cg = cooperative_groups;

#define Bsz 256
#define Tsz 512
#define GSTR 258    // gate-accum row stride (floats): 2-way LDS alias only (free)

using half8 = __attribute__((ext_vector_type(8))) _Float16;
using half4 = __attribute__((ext_vector_type(4))) _Float16;
using f32x4 = __attribute__((ext_vector_type(4))) float;

#define MFMA_V(acc, a, b) (acc) = __builtin_amdgcn_mfma_f32_16x16x32_f16((a), (b), (acc), 0, 0, 0)
#define INV2048 (1.0f / 2048.0f)

__device__ __forceinline__ float sigm(float v)   { return 1.0f / (1.0f + expf(-v)); }
__device__ __forceinline__ float tanh_f(float v) { float e = expf(2.0f * v); return 1.0f - 2.0f / (e + 1.0f); }

__device__ __forceinline__ void split8(const float* p, half8& hi, half8& lo) {
    float4 v0 = *(const float4*)p, v1 = *(const float4*)(p + 4);
    float vv[8] = {v0.x, v0.y, v0.z, v0.w, v1.x, v1.y, v1.z, v1.w};
    #pragma unroll
    for (int j = 0; j < 8; ++j) {
        hi[j] = (_Float16)vv[j];
        lo[j] = (_Float16)((vv[j] - (float)hi[j]) * 2048.0f);
    }
}

// Write-through stores: agent-scope relaxed atomic stores compile to sc1-flagged
// global stores -> visible at the device-coherent point (IF) without any wbL2.
__device__ __forceinline__ void st_h4(_Float16* p, half4 v) {
    unsigned long long u;
    __builtin_memcpy(&u, &v, 8);
    __hip_atomic_store((unsigned long long*)(void*)p, u,
                       __ATOMIC_RELAXED, __HIP_MEMORY_SCOPE_AGENT);
}
__device__ __forceinline__ void st_f(float* p, float v) {
    __hip_atomic_store(p, v, __ATOMIC_RELAXED, __HIP_MEMORY_SCOPE_AGENT);
}

// ---------------------------------------------------------------------------
// Step barrier (R12): relaxed 2-level arrival every step + own-L1 inv; the
// per-XCD leader wbL2+invL2 only every 4th step (4-slot buffer rotation keeps
// reader-side L2 staleness safe at reuse distance 4).
// ---------------------------------------------------------------------------
__device__ __forceinline__ void step_barrier(unsigned* bar0, unsigned* bar1,
                                             unsigned* phase2, unsigned* dummyv,
                                             int bx, int isLead, unsigned xcc,
                                             unsigned nLead, unsigned it1) {
    __syncthreads();   // all waves' stores drained (vmcnt 0) -> at coherent point
    if (threadIdx.x == 0) {
        unsigned old = __hip_atomic_fetch_add(&bar0[(bx & 15) << 5], 1u,
                                              __ATOMIC_RELAXED, __HIP_MEMORY_SCOPE_AGENT);
        if ((old & 15u) == 15u)
            __hip_atomic_fetch_add(bar1, 1u, __ATOMIC_RELAXED, __HIP_MEMORY_SCOPE_AGENT);
        const bool l2i = (it1 & 3u) == 0u;          // steps it ≡ 3 (mod 4)
        if (l2i) {
            if (isLead) {
                while (__hip_atomic_load(bar1, __ATOMIC_RELAXED, __HIP_MEMORY_SCOPE_AGENT) < 16u * it1)
                    __builtin_amdgcn_s_sleep(1);
                // the ONE wbL2+invL2 for this XCD (ACQ_REL RMW on XCD-private line)
                __hip_atomic_fetch_add(&dummyv[xcc << 5], 1u,
                                       __ATOMIC_ACQ_REL, __HIP_MEMORY_SCOPE_AGENT);
                __hip_atomic_fetch_add(phase2, 1u,
                                       __ATOMIC_RELAXED, __HIP_MEMORY_SCOPE_AGENT);
            }
            while (__hip_atomic_load(phase2, __ATOMIC_RELAXED, __HIP_MEMORY_SCOPE_AGENT) < nLead * (it1 >> 2))
                __builtin_amdgcn_s_sleep(1);
        } else {
            while (__hip_atomic_load(bar1, __ATOMIC_RELAXED, __HIP_MEMORY_SCOPE_AGENT) < 16u * it1)
                __builtin_amdgcn_s_sleep(1);
        }
        asm volatile("buffer_inv sc0" ::: "memory");   // own-CU L1 invalidate
    }
    __syncthreads();
}

// ---------------------------------------------------------------------------
// Persistent 2-layer LSTM, BLOCK-SPECIALIZED + pipelined, 1 barrier/step.
// R13 = R12 + hoisted B-operand loads: all kt loads of a bi-tile issue
// back-to-back into register arrays before the MFMA block (one latency wait
// per bi-tile instead of per kt; ~8x deeper memory-level parallelism).
// L1 path: bh[4]/bl[4], unroll 2. L2 path: bh[8]/bl[8], unroll 1 (register
// budget: 128 weight AGPRs + 64 load VGPRs + acc fits the 256 unified budget).
// ---------------------------------------------------------------------------
__global__ __launch_bounds__(512, 1) void lstm_persist(
    const float* __restrict__ x,
    const float* __restrict__ W_ih1, const float* __restrict__ W_hh1,
    const float* __restrict__ b_ih1, const float* __restrict__ b_hh1,
    const float* __restrict__ W_ih2, const float* __restrict__ W_hh2,
    const float* __restrict__ b_ih2, const float* __restrict__ b_hh2,
    const float* __restrict__ W_out, const float* __restrict__ b_out,
    float* __restrict__ out, char* __restrict__ ws)
{
    __shared__ float gAcc[32 * GSTR];   // gate accumulator [perm row][b]
    __shared__ float poArr[2 * GSTR];   // out-projection partials (L2 blocks)
    __shared__ float bp[32], wihp[32], woutp[8];
    __shared__ float bouts_s;
    __shared__ unsigned isLead_s, xcc_s, nLead_s;

    cg::grid_group grid = cg::this_grid();

    const int tid  = threadIdx.x;
    const int lane = tid & 63;
    const int wv   = tid >> 6;        // 0..7: K-split index
    const int m    = lane & 15;
    const int quad = lane >> 4;
    const int bx   = blockIdx.x;
    const bool isL2 = (bx >= 128);
    const int rg   = isL2 ? (bx - 128) : bx;   // row-group 0..127 within layer
    const int HO   = rg << 3;                  // first hidden unit

    // ---- workspace --------------------------------------------------------
    float*    xT       = (float*)ws;                                  // [512][256]
    _Float16* hswz     = (_Float16*)(ws + (512 << 10));               // 16 x 512KB (4 slots x {h1,h2} x {hi,lo})
    float*    partials = (float*)(ws + (512 << 10) + (8 << 20));      // [4 slot][256 b][128 rg]
    unsigned* bar0     = (unsigned*)(ws + (512 << 10) + (8 << 20) + (512 << 10));
    unsigned* bar1     = bar0 + 1024;
    unsigned* phase2   = bar0 + 1056;
    unsigned* nLeadCt  = bar0 + 1057;
    unsigned* claimA   = bar0 + 1088;   // + (xcc<<5)
    unsigned* dummyv   = bar0 + 1536;   // + (xcc<<5)

    #define HBUF(p, l, hl) (hswz + ((((p) << 2) | ((l) << 1) | (hl)) << 18))

    // ---- pre-loop init ----------------------------------------------------
    if (bx == 0)
        for (int i = tid; i < 2048; i += 512) bar0[i] = 0u;   // all counters
    if (tid < 32) {
        const int row = ((tid & 3) << 10) + HO + (tid >> 2);  // perm row -> orig row
        if (!isL2) {
            bp[tid]   = b_ih1[row] + b_hh1[row];
            wihp[tid] = W_ih1[row];
        } else {
            bp[tid] = b_ih2[row] + b_hh2[row];
            if (tid < 8) woutp[tid] = W_out[HO + tid];
        }
        if (tid == 0) bouts_s = b_out[0];
    }
    {
        const int gidx = bx * 512 + tid;                 // 0..131071
        // zero slot-3 region (h1(-1), h2(-1), hi+lo): bytes [6MB, 8MB)
        *(float4*)((char*)hswz + (6u << 20) + (size_t)gidx * 16) = make_float4(0, 0, 0, 0);
        xT[gidx] = x[(gidx & 255) * Tsz + (gidx >> 8)];  // xT[t][b]
    }

    grid.sync();   // heavy sync #1: xT, zeros, counters visible (release -> IF)

    // ---- leader election by PHYSICAL XCD id -------------------------------
    if (tid == 0) {
        unsigned xcc;
        asm volatile("s_getreg_b32 %0, hwreg(HW_REG_XCC_ID)" : "=s"(xcc));
        xcc &= 7u;
        xcc_s = xcc;
        unsigned old = __hip_atomic_fetch_add(&claimA[xcc << 5], 1u,
                                              __ATOMIC_RELAXED, __HIP_MEMORY_SCOPE_AGENT);
        isLead_s = (old == 0u);
        if (old == 0u)
            __hip_atomic_fetch_add(nLeadCt, 1u,
                                   __ATOMIC_RELAXED, __HIP_MEMORY_SCOPE_AGENT);
    }
    grid.sync();   // heavy sync #2: all elections final
    if (tid == 0)
        nLead_s = __hip_atomic_load(nLeadCt, __ATOMIC_RELAXED, __HIP_MEMORY_SCOPE_AGENT);
    __syncthreads();
    const int      isLead = (int)isLead_s;
    const unsigned xcc    = xcc_s;
    const unsigned nLead  = nLead_s;

    const int b_ep = tid & 255, hg = tid >> 8;           // epilogue: batch, hidden-quad
    const int k0e  = HO + (hg << 2);
    const int wofs = ((b_ep >> 4) << 14) + ((k0e >> 5) << 9)
                   + (((b_ep & 15) | (((k0e >> 3) & 3) << 4)) << 3) + (k0e & 7);

    if (!isL2) {
        // ==================== LAYER-1 BLOCKS ===============================
        half8 wh[2][4], wl[2][4];     // 64 regs/wave, K-slice 128
        #pragma unroll
        for (int mt = 0; mt < 2; ++mt) {
            const int pr = (mt << 4) + m;
            const size_t rw = (size_t)(((pr & 3) << 10) + HO + (pr >> 2)) << 10;
            #pragma unroll
            for (int kt = 0; kt < 4; ++kt) {
                const int k = (wv << 7) + (kt << 5) + (quad << 3);
                split8(W_hh1 + rw + k, wh[mt][kt], wl[mt][kt]);
            }
        }
        for (int idx = tid; idx < 8192; idx += 512) {    // gAcc init for it=0
            const int p = idx >> 8, b = idx & 255;
            gAcc[p * GSTR + b] = bp[p] + xT[b] * wihp[p];
        }
        __syncthreads();
        float cr[4] = {0, 0, 0, 0};

        for (int it = 0; it <= Tsz; ++it) {
            const int sW = it & 3;          // h1(it) write slot
            const int sR = (it + 3) & 3;    // h1(it-1) read slot
            const int sP = it & 3;          // partials read slot (col t=it-2)

            float xnext = 0.0f;
            if (it + 1 < Tsz) xnext = xT[((it + 1) << 8) + b_ep];

            if (wv == 0 && it >= 2) {                    // out column t=it-2
                const float* pp = partials + (sP << 15) + (bx << 7);
                float s = pp[lane] + pp[lane + 64];
                s += __shfl_xor(s, 32); s += __shfl_xor(s, 16); s += __shfl_xor(s, 8);
                s += __shfl_xor(s, 4);  s += __shfl_xor(s, 2);  s += __shfl_xor(s, 1);
                if (lane == 0) st_f(&out[(bx << 9) + (it - 2)], bouts_s + s);
            }

            // gates1(it) += Whh1 . h1(it-1)
            if (it < Tsz) {
                const _Float16* bhB = HBUF(sR, 0, 0);
                const _Float16* blB = HBUF(sR, 0, 1);
                const int lo_off = (wv << 11) + (lane << 3);
                #pragma unroll 2
                for (int bi = 0; bi < 16; ++bi) {
                    const int btl = (bi + (wv << 1)) & 15;
                    const _Float16* ph = bhB + (btl << 14) + lo_off;
                    const _Float16* pl = blB + (btl << 14) + lo_off;
                    half8 bh[4], bl[4];
                    #pragma unroll
                    for (int kt = 0; kt < 4; ++kt) {
                        bh[kt] = *(const half8*)(ph + (kt << 9));
                        bl[kt] = *(const half8*)(pl + (kt << 9));
                    }
                    f32x4 a0[2] = {(f32x4){0,0,0,0}, (f32x4){0,0,0,0}};
                    f32x4 a1[2] = {(f32x4){0,0,0,0}, (f32x4){0,0,0,0}};
                    #pragma unroll
                    for (int kt = 0; kt < 4; ++kt) {
                        MFMA_V(a0[0], wh[0][kt], bh[kt]);
                        MFMA_V(a1[0], wh[0][kt], bl[kt]);
                        MFMA_V(a1[0], wl[0][kt], bh[kt]);
                        MFMA_V(a0[1], wh[1][kt], bh[kt]);
                        MFMA_V(a1[1], wh[1][kt], bl[kt]);
                        MFMA_V(a1[1], wl[1][kt], bh[kt]);
                    }
                    const int col = (btl << 4) + m;
                    #pragma unroll
                    for (int mt = 0; mt < 2; ++mt)
                        #pragma unroll
                        for (int r = 0; r < 4; ++r)
                            atomicAdd(&gAcc[((mt << 4) + (quad << 2) + r) * GSTR + col],
                                      a0[mt][r] + a1[mt][r] * INV2048);
                }
            }

            __syncthreads();

            if (it < Tsz) {            // layer-1 cell -> h1(it) @slot sW
                half4 hhi, hlo;
                #pragma unroll
                for (int j = 0; j < 4; ++j) {
                    const int p = (hg << 4) + (j << 2);
                    const float gi = gAcc[(p + 0) * GSTR + b_ep];
                    const float gf = gAcc[(p + 1) * GSTR + b_ep];
                    const float gg = gAcc[(p + 2) * GSTR + b_ep];
                    const float go = gAcc[(p + 3) * GSTR + b_ep];
                    const float c  = sigm(gf) * cr[j] + sigm(gi) * tanh_f(gg);
                    cr[j] = c;
                    const float hn = sigm(go) * tanh_f(c);
                    hhi[j] = (_Float16)hn;
                    hlo[j] = (_Float16)((hn - (float)hhi[j]) * 2048.0f);
                }
                st_h4(HBUF(sW, 0, 0) + wofs, hhi);
                st_h4(HBUF(sW, 0, 1) + wofs, hlo);
                if (it + 1 < Tsz) {
                    #pragma unroll
                    for (int p = (hg << 4); p < (hg << 4) + 16; ++p)
                        gAcc[p * GSTR + b_ep] = bp[p] + xnext * wihp[p];
                }
            }

            step_barrier(bar0, bar1, phase2, dummyv, bx, isLead, xcc, nLead,
                         (unsigned)(it + 1));
        }
    } else {
        // ==================== LAYER-2 BLOCKS ===============================
        half8 wh[2][8], wl[2][8];     // 128 regs/wave, K-slice 256
        #pragma unroll
        for (int mt = 0; mt < 2; ++mt) {
            const int pr = (mt << 4) + m;
            const size_t rw = (size_t)(((pr & 3) << 10) + HO + (pr >> 2)) << 10;
            #pragma unroll
            for (int kt = 0; kt < 8; ++kt) {
                const int k = (wv << 8) + (kt << 5) + (quad << 3);
                const float* p = (k < 1024) ? (W_ih2 + rw + k)
                                            : (W_hh2 + rw + k - 1024);
                split8(p, wh[mt][kt], wl[mt][kt]);
            }
        }
        for (int idx = tid; idx < 8192; idx += 512) {    // gAcc init
            const int p = idx >> 8, b = idx & 255;
            gAcc[p * GSTR + b] = bp[p];
        }
        __syncthreads();
        float cr[4] = {0, 0, 0, 0};

        for (int it = 0; it <= Tsz; ++it) {
            const int sR1 = (it + 3) & 3;   // h1(it-1) read slot
            const int sW2 = (it + 3) & 3;   // h2(it-1) write slot
            const int sR2 = (it + 2) & 3;   // h2(it-2) read slot
            const int sP  = it & 3;         // partials read slot
            const int sPW = (it + 1) & 3;   // partials write slot

            if (wv == 0 && it >= 2) {                    // out column t=it-2
                const float* pp = partials + (sP << 15) + (bx << 7);
                float s = pp[lane] + pp[lane + 64];
                s += __shfl_xor(s, 32); s += __shfl_xor(s, 16); s += __shfl_xor(s, 8);
                s += __shfl_xor(s, 4);  s += __shfl_xor(s, 2);  s += __shfl_xor(s, 1);
                if (lane == 0) st_f(&out[(bx << 9) + (it - 2)], bouts_s + s);
            }

            // gates2(it-1) += W2 . [h1(it-1); h2(it-2)]
            if (it >= 1) {
                const bool hi2 = (wv >= 4);
                const _Float16* bhB = hi2 ? HBUF(sR2, 1, 0) : HBUF(sR1, 0, 0);
                const _Float16* blB = hi2 ? HBUF(sR2, 1, 1) : HBUF(sR1, 0, 1);
                const int lo_off = ((wv & 3) << 12) + (lane << 3);
                #pragma unroll 1
                for (int bi = 0; bi < 16; ++bi) {
                    const int btl = (bi + (wv << 1)) & 15;
                    const _Float16* ph = bhB + (btl << 14) + lo_off;
                    const _Float16* pl = blB + (btl << 14) + lo_off;
                    half8 bh[8], bl[8];
                    #pragma unroll
                    for (int kt = 0; kt < 8; ++kt) {
                        bh[kt] = *(const half8*)(ph + (kt << 9));
                        bl[kt] = *(const half8*)(pl + (kt << 9));
                    }
                    f32x4 a0[2] = {(f32x4){0,0,0,0}, (f32x4){0,0,0,0}};
                    f32x4 a1[2] = {(f32x4){0,0,0,0}, (f32x4){0,0,0,0}};
                    #pragma unroll
                    for (int kt = 0; kt < 8; ++kt) {
                        MFMA_V(a0[0], wh[0][kt], bh[kt]);
                        MFMA_V(a1[0], wh[0][kt], bl[kt]);
                        MFMA_V(a1[0], wl[0][kt], bh[kt]);
                        MFMA_V(a0[1], wh[1][kt], bh[kt]);
                        MFMA_V(a1[1], wh[1][kt], bl[kt]);
                        MFMA_V(a1[1], wl[1][kt], bh[kt]);
                    }
                    const int col = (btl << 4) + m;
                    #pragma unroll
                    for (int mt = 0; mt < 2; ++mt)
                        #pragma unroll
                        for (int r = 0; r < 4; ++r)
                            atomicAdd(&gAcc[((mt << 4) + (quad << 2) + r) * GSTR + col],
                                      a0[mt][r] + a1[mt][r] * INV2048);
                }
            }

            __syncthreads();

            if (it >= 1) {             // layer-2 cell for t=it-1 -> h2(it-1) @slot sW2
                half4 hhi, hlo;
                float po = 0.0f;
                #pragma unroll
                for (int j = 0; j < 4; ++j) {
                    const int p = (hg << 4) + (j << 2);
                    const float gi = gAcc[(p + 0) * GSTR + b_ep];
                    const float gf = gAcc[(p + 1) * GSTR + b_ep];
                    const float gg = gAcc[(p + 2) * GSTR + b_ep];
                    const float go = gAcc[(p + 3) * GSTR + b_ep];
                    const float c  = sigm(gf) * cr[j] + sigm(gi) * tanh_f(gg);
                    cr[j] = c;
                    const float hn = sigm(go) * tanh_f(c);
                    hhi[j] = (_Float16)hn;
                    hlo[j] = (_Float16)((hn - (float)hhi[j]) * 2048.0f);
                    po += hn * woutp[(hg << 2) + j];
                }
                st_h4(HBUF(sW2, 1, 0) + wofs, hhi);
                st_h4(HBUF(sW2, 1, 1) + wofs, hlo);
                poArr[hg * GSTR + b_ep] = po;
                #pragma unroll
                for (int p = (hg << 4); p < (hg << 4) + 16; ++p)
                    gAcc[p * GSTR + b_ep] = bp[p];
            }
            __syncthreads();
            if (it >= 1 && tid < 256) {   // partials[sPW][b][rg]
                const float s = poArr[tid] + poArr[GSTR + tid];
                st_f(&partials[(sPW << 15) + (tid << 7) + rg], s);
            }

            step_barrier(bar0, bar1, phase2, dummyv, bx, isLead, xcc, nLead,
                         (unsigned)(it + 1));
        }
    }

    // tail: out column t=511 (partials slot (512+1)&3 = 1, written at it=512)
    if (wv == 0) {
        const float* pp = partials + (1 << 15) + (bx << 7);
        float s = pp[lane] + pp[lane + 64];
        s += __shfl_xor(s, 32); s += __shfl_xor(s, 16); s += __shfl_xor(s, 8);
        s += __shfl_xor(s, 4);  s += __shfl_xor(s, 2);  s += __shfl_xor(s, 1);
        if (lane == 0) st_f(&out[(bx << 9) + (Tsz - 1)], bouts_s + s);
    }
    #undef HBUF
}

// ---------------------------------------------------------------------------
extern "C" void kernel_launch(void* const* d_in, const int* in_sizes, int n_in,
                              void* d_out, int out_size, void* d_ws, size_t ws_size,
                              hipStream_t stream)
{
    const float* x     = (const float*)d_in[0];
    const float* W_ih1 = (const float*)d_in[1];
    const float* W_hh1 = (const float*)d_in[2];
    const float* b_ih1 = (const float*)d_in[3];
    const float* b_hh1 = (const float*)d_in[4];
    const float* W_ih2 = (const float*)d_in[5];
    const float* W_hh2 = (const float*)d_in[6];
    const float* b_ih2 = (const float*)d_in[7];
    const float* b_hh2 = (const float*)d_in[8];
    const float* W_out = (const float*)d_in[9];
    const float* b_out = (const float*)d_in[10];
    float* out = (float*)d_out;
    char*  ws  = (char*)d_ws;

    void* args[] = {
        (void*)&x,
        (void*)&W_ih1, (void*)&W_hh1, (void*)&b_ih1, (void*)&b_hh1,
        (void*)&W_ih2, (void*)&W_hh2, (void*)&b_ih2, (void*)&b_hh2,
        (void*)&W_out, (void*)&b_out, (void*)&out, (void*)&ws,
    };
    hipLaunchCooperativeKernel((const void*)lstm_persist,
                               dim3(256), dim3(512), args, 0, stream);
}

// Round 6
// 45883.145 us; speedup vs baseline: 1.0086x; 1.0086x over previous
//
#include <hip/hip_runtime.h>
#include <hip/hip_cooperative_groups.h>
#include <math.h>

namespace cg = cooperative_groups;

#define Bsz 256
#define Tsz 512
#define GSTR 258    // gate-accum row stride (floats): 2-way LDS alias only (free)

using half8 = __attribute__((ext_vector_type(8))) _Float16;
using half4 = __attribute__((ext_vector_type(4))) _Float16;
using f32x4 = __attribute__((ext_vector_type(4))) float;

#define MFMA_V(acc, a, b) (acc) = __builtin_amdgcn_mfma_f32_16x16x32_f16((a), (b), (acc), 0, 0, 0)
#define INV2048 (1.0f / 2048.0f)

__device__ __forceinline__ float sigm(float v)   { return 1.0f / (1.0f + expf(-v)); }
__device__ __forceinline__ float tanh_f(float v) { float e = expf(2.0f * v); return 1.0f - 2.0f / (e + 1.0f); }

__device__ __forceinline__ void split8(const float* p, half8& hi, half8& lo) {
    float4 v0 = *(const float4*)p, v1 = *(const float4*)(p + 4);
    float vv[8] = {v0.x, v0.y, v0.z, v0.w, v1.x, v1.y, v1.z, v1.w};
    #pragma unroll
    for (int j = 0; j < 8; ++j) {
        hi[j] = (_Float16)vv[j];
        lo[j] = (_Float16)((vv[j] - (float)hi[j]) * 2048.0f);
    }
}

// Write-through stores: agent-scope relaxed atomic stores compile to sc1-flagged
// global stores -> visible at the device-coherent point (IF) without any wbL2.
__device__ __forceinline__ void st_h4(_Float16* p, half4 v) {
    unsigned long long u;
    __builtin_memcpy(&u, &v, 8);
    __hip_atomic_store((unsigned long long*)(void*)p, u,
                       __ATOMIC_RELAXED, __HIP_MEMORY_SCOPE_AGENT);
}
__device__ __forceinline__ void st_f(float* p, float v) {
    __hip_atomic_store(p, v, __ATOMIC_RELAXED, __HIP_MEMORY_SCOPE_AGENT);
}

// Agent-scope helpers (the ONLY cross-block sync primitives used — these are
// the R0-R13-proven ones; workgroup-scope-on-global was R14's deadlock).
__device__ __forceinline__ unsigned ag_add(unsigned* p, unsigned v) {
    return __hip_atomic_fetch_add(p, v, __ATOMIC_RELAXED, __HIP_MEMORY_SCOPE_AGENT);
}
__device__ __forceinline__ unsigned ag_ld(unsigned* p) {
    return __hip_atomic_load(p, __ATOMIC_RELAXED, __HIP_MEMORY_SCOPE_AGENT);
}

// ---------------------------------------------------------------------------
// Step barrier, R15: hierarchical (as R14) but ALL agent-scope.
//  1) each block's tid0 adds 1 to its XCD's arrival line (8 lines, 32 RMW each
//     -- vs R12/R13's 256 RMW onto 17 lines feeding ONE bar1 line).
//  2) per-XCD leader polls its arrival line; when nBlkX arrived, ONE add to
//     bar1 and polls it (8 atomics + 8 pollers on the global line, not 256).
//  3) every 4th step: leader's wbL2+invL2 (reader-side staleness, 4-slot rot).
//  4) leader bumps per-XCD release flag; 31 followers poll it at s_sleep(4)
//     (~0.3us quantum: 8x less poll traffic, negligible added latency).
// Deadlock-safety: monotone counters only, same gating logic as R12/R13.
// ---------------------------------------------------------------------------
__device__ __forceinline__ void step_barrier(unsigned* arrX, unsigned* flagX,
                                             unsigned* bar1, unsigned* dummyv,
                                             int isLead, unsigned xcc,
                                             unsigned nLead, unsigned nBlkX,
                                             unsigned it1) {
    __syncthreads();   // all waves' stores drained (vmcnt 0) -> at coherent point
    if (threadIdx.x == 0) {
        ag_add(&arrX[xcc << 5], 1u);                      // arrival, per-XCD line
        if (isLead) {
            while (ag_ld(&arrX[xcc << 5]) < nBlkX * it1)
                __builtin_amdgcn_s_sleep(1);
            ag_add(bar1, 1u);
            while (ag_ld(bar1) < nLead * it1)
                __builtin_amdgcn_s_sleep(1);
            if ((it1 & 3u) == 0u)      // steps it ≡ 3 (mod 4): the ONE wbL2+invL2
                __hip_atomic_fetch_add(&dummyv[xcc << 5], 1u,
                                       __ATOMIC_ACQ_REL, __HIP_MEMORY_SCOPE_AGENT);
            ag_add(&flagX[xcc << 5], 1u);                 // release, per-XCD line
        } else {
            while (ag_ld(&flagX[xcc << 5]) < it1)
                __builtin_amdgcn_s_sleep(4);
        }
        asm volatile("buffer_inv sc0" ::: "memory");      // own-CU L1 invalidate
    }
    __syncthreads();
}

// ---------------------------------------------------------------------------
// Persistent 2-layer LSTM, BLOCK-SPECIALIZED + pipelined, 1 barrier/step.
// R15 = R13 + agent-scope hierarchical barrier (fabric convoy reduction).
// ---------------------------------------------------------------------------
__global__ __launch_bounds__(512, 1) void lstm_persist(
    const float* __restrict__ x,
    const float* __restrict__ W_ih1, const float* __restrict__ W_hh1,
    const float* __restrict__ b_ih1, const float* __restrict__ b_hh1,
    const float* __restrict__ W_ih2, const float* __restrict__ W_hh2,
    const float* __restrict__ b_ih2, const float* __restrict__ b_hh2,
    const float* __restrict__ W_out, const float* __restrict__ b_out,
    float* __restrict__ out, char* __restrict__ ws)
{
    __shared__ float gAcc[32 * GSTR];   // gate accumulator [perm row][b]
    __shared__ float poArr[2 * GSTR];   // out-projection partials (L2 blocks)
    __shared__ float bp[32], wihp[32], woutp[8];
    __shared__ float bouts_s;
    __shared__ unsigned isLead_s, xcc_s, nLead_s, nBlkX_s;

    cg::grid_group grid = cg::this_grid();

    const int tid  = threadIdx.x;
    const int lane = tid & 63;
    const int wv   = tid >> 6;        // 0..7: K-split index
    const int m    = lane & 15;
    const int quad = lane >> 4;
    const int bx   = blockIdx.x;
    const bool isL2 = (bx >= 128);
    const int rg   = isL2 ? (bx - 128) : bx;   // row-group 0..127 within layer
    const int HO   = rg << 3;                  // first hidden unit

    // ---- workspace --------------------------------------------------------
    float*    xT       = (float*)ws;                                  // [512][256]
    _Float16* hswz     = (_Float16*)(ws + (512 << 10));               // 16 x 512KB (4 slots x {h1,h2} x {hi,lo})
    float*    partials = (float*)(ws + (512 << 10) + (8 << 20));      // [4 slot][256 b][128 rg]
    unsigned* bar0     = (unsigned*)(ws + (512 << 10) + (8 << 20) + (512 << 10));
    unsigned* arrX     = bar0 + 512;    // + (xcc<<5): per-XCD arrival counters
    unsigned* flagX    = bar0 + 768;    // + (xcc<<5): per-XCD release flags
    unsigned* bar1     = bar0 + 1024;
    unsigned* nLeadCt  = bar0 + 1057;
    unsigned* claimA   = bar0 + 1088;   // + (xcc<<5)
    unsigned* dummyv   = bar0 + 1536;   // + (xcc<<5)

    #define HBUF(p, l, hl) (hswz + ((((p) << 2) | ((l) << 1) | (hl)) << 18))

    // ---- pre-loop init ----------------------------------------------------
    if (bx == 0)
        for (int i = tid; i < 2048; i += 512) bar0[i] = 0u;   // all counters
    if (tid < 32) {
        const int row = ((tid & 3) << 10) + HO + (tid >> 2);  // perm row -> orig row
        if (!isL2) {
            bp[tid]   = b_ih1[row] + b_hh1[row];
            wihp[tid] = W_ih1[row];
        } else {
            bp[tid] = b_ih2[row] + b_hh2[row];
            if (tid < 8) woutp[tid] = W_out[HO + tid];
        }
        if (tid == 0) bouts_s = b_out[0];
    }
    {
        const int gidx = bx * 512 + tid;                 // 0..131071
        // zero slot-3 region (h1(-1), h2(-1), hi+lo): bytes [6MB, 8MB)
        *(float4*)((char*)hswz + (6u << 20) + (size_t)gidx * 16) = make_float4(0, 0, 0, 0);
        xT[gidx] = x[(gidx & 255) * Tsz + (gidx >> 8)];  // xT[t][b]
    }

    grid.sync();   // heavy sync #1: xT, zeros, counters visible (release -> IF)

    // ---- leader election by PHYSICAL XCD id -------------------------------
    if (tid == 0) {
        unsigned xcc;
        asm volatile("s_getreg_b32 %0, hwreg(HW_REG_XCC_ID)" : "=s"(xcc));
        xcc &= 7u;
        xcc_s = xcc;
        unsigned old = ag_add(&claimA[xcc << 5], 1u);
        isLead_s = (old == 0u);
        if (old == 0u)
            ag_add(nLeadCt, 1u);
    }
    grid.sync();   // heavy sync #2: all elections final
    if (tid == 0) {
        nLead_s = ag_ld(nLeadCt);
        nBlkX_s = ag_ld(&claimA[xcc_s << 5]);
    }
    __syncthreads();
    const int      isLead = (int)isLead_s;
    const unsigned xcc    = xcc_s;
    const unsigned nLead  = nLead_s;
    const unsigned nBlkX  = nBlkX_s;

    const int b_ep = tid & 255, hg = tid >> 8;           // epilogue: batch, hidden-quad
    const int k0e  = HO + (hg << 2);
    const int wofs = ((b_ep >> 4) << 14) + ((k0e >> 5) << 9)
                   + (((b_ep & 15) | (((k0e >> 3) & 3) << 4)) << 3) + (k0e & 7);

    if (!isL2) {
        // ==================== LAYER-1 BLOCKS ===============================
        half8 wh[2][4], wl[2][4];     // 64 regs/wave, K-slice 128
        #pragma unroll
        for (int mt = 0; mt < 2; ++mt) {
            const int pr = (mt << 4) + m;
            const size_t rw = (size_t)(((pr & 3) << 10) + HO + (pr >> 2)) << 10;
            #pragma unroll
            for (int kt = 0; kt < 4; ++kt) {
                const int k = (wv << 7) + (kt << 5) + (quad << 3);
                split8(W_hh1 + rw + k, wh[mt][kt], wl[mt][kt]);
            }
        }
        for (int idx = tid; idx < 8192; idx += 512) {    // gAcc init for it=0
            const int p = idx >> 8, b = idx & 255;
            gAcc[p * GSTR + b] = bp[p] + xT[b] * wihp[p];
        }
        __syncthreads();
        float cr[4] = {0, 0, 0, 0};

        for (int it = 0; it <= Tsz; ++it) {
            const int sW = it & 3;          // h1(it) write slot
            const int sR = (it + 3) & 3;    // h1(it-1) read slot
            const int sP = it & 3;          // partials read slot (col t=it-2)

            float xnext = 0.0f;
            if (it + 1 < Tsz) xnext = xT[((it + 1) << 8) + b_ep];

            if (wv == 0 && it >= 2) {                    // out column t=it-2
                const float* pp = partials + (sP << 15) + (bx << 7);
                float s = pp[lane] + pp[lane + 64];
                s += __shfl_xor(s, 32); s += __shfl_xor(s, 16); s += __shfl_xor(s, 8);
                s += __shfl_xor(s, 4);  s += __shfl_xor(s, 2);  s += __shfl_xor(s, 1);
                if (lane == 0) st_f(&out[(bx << 9) + (it - 2)], bouts_s + s);
            }

            // gates1(it) += Whh1 . h1(it-1)
            if (it < Tsz) {
                const _Float16* bhB = HBUF(sR, 0, 0);
                const _Float16* blB = HBUF(sR, 0, 1);
                const int lo_off = (wv << 11) + (lane << 3);
                #pragma unroll 2
                for (int bi = 0; bi < 16; ++bi) {
                    const int btl = (bi + (wv << 1)) & 15;
                    const _Float16* ph = bhB + (btl << 14) + lo_off;
                    const _Float16* pl = blB + (btl << 14) + lo_off;
                    half8 bh[4], bl[4];
                    #pragma unroll
                    for (int kt = 0; kt < 4; ++kt) {
                        bh[kt] = *(const half8*)(ph + (kt << 9));
                        bl[kt] = *(const half8*)(pl + (kt << 9));
                    }
                    f32x4 a0[2] = {(f32x4){0,0,0,0}, (f32x4){0,0,0,0}};
                    f32x4 a1[2] = {(f32x4){0,0,0,0}, (f32x4){0,0,0,0}};
                    #pragma unroll
                    for (int kt = 0; kt < 4; ++kt) {
                        MFMA_V(a0[0], wh[0][kt], bh[kt]);
                        MFMA_V(a1[0], wh[0][kt], bl[kt]);
                        MFMA_V(a1[0], wl[0][kt], bh[kt]);
                        MFMA_V(a0[1], wh[1][kt], bh[kt]);
                        MFMA_V(a1[1], wh[1][kt], bl[kt]);
                        MFMA_V(a1[1], wl[1][kt], bh[kt]);
                    }
                    const int col = (btl << 4) + m;
                    #pragma unroll
                    for (int mt = 0; mt < 2; ++mt)
                        #pragma unroll
                        for (int r = 0; r < 4; ++r)
                            atomicAdd(&gAcc[((mt << 4) + (quad << 2) + r) * GSTR + col],
                                      a0[mt][r] + a1[mt][r] * INV2048);
                }
            }

            __syncthreads();

            if (it < Tsz) {            // layer-1 cell -> h1(it) @slot sW
                half4 hhi, hlo;
                #pragma unroll
                for (int j = 0; j < 4; ++j) {
                    const int p = (hg << 4) + (j << 2);
                    const float gi = gAcc[(p + 0) * GSTR + b_ep];
                    const float gf = gAcc[(p + 1) * GSTR + b_ep];
                    const float gg = gAcc[(p + 2) * GSTR + b_ep];
                    const float go = gAcc[(p + 3) * GSTR + b_ep];
                    const float c  = sigm(gf) * cr[j] + sigm(gi) * tanh_f(gg);
                    cr[j] = c;
                    const float hn = sigm(go) * tanh_f(c);
                    hhi[j] = (_Float16)hn;
                    hlo[j] = (_Float16)((hn - (float)hhi[j]) * 2048.0f);
                }
                st_h4(HBUF(sW, 0, 0) + wofs, hhi);
                st_h4(HBUF(sW, 0, 1) + wofs, hlo);
                if (it + 1 < Tsz) {
                    #pragma unroll
                    for (int p = (hg << 4); p < (hg << 4) + 16; ++p)
                        gAcc[p * GSTR + b_ep] = bp[p] + xnext * wihp[p];
                }
            }

            step_barrier(arrX, flagX, bar1, dummyv, isLead, xcc, nLead, nBlkX,
                         (unsigned)(it + 1));
        }
    } else {
        // ==================== LAYER-2 BLOCKS ===============================
        half8 wh[2][8], wl[2][8];     // 128 regs/wave, K-slice 256
        #pragma unroll
        for (int mt = 0; mt < 2; ++mt) {
            const int pr = (mt << 4) + m;
            const size_t rw = (size_t)(((pr & 3) << 10) + HO + (pr >> 2)) << 10;
            #pragma unroll
            for (int kt = 0; kt < 8; ++kt) {
                const int k = (wv << 8) + (kt << 5) + (quad << 3);
                const float* p = (k < 1024) ? (W_ih2 + rw + k)
                                            : (W_hh2 + rw + k - 1024);
                split8(p, wh[mt][kt], wl[mt][kt]);
            }
        }
        for (int idx = tid; idx < 8192; idx += 512) {    // gAcc init
            const int p = idx >> 8, b = idx & 255;
            gAcc[p * GSTR + b] = bp[p];
        }
        __syncthreads();
        float cr[4] = {0, 0, 0, 0};

        for (int it = 0; it <= Tsz; ++it) {
            const int sR1 = (it + 3) & 3;   // h1(it-1) read slot
            const int sW2 = (it + 3) & 3;   // h2(it-1) write slot
            const int sR2 = (it + 2) & 3;   // h2(it-2) read slot
            const int sP  = it & 3;         // partials read slot
            const int sPW = (it + 1) & 3;   // partials write slot

            if (wv == 0 && it >= 2) {                    // out column t=it-2
                const float* pp = partials + (sP << 15) + (bx << 7);
                float s = pp[lane] + pp[lane + 64];
                s += __shfl_xor(s, 32); s += __shfl_xor(s, 16); s += __shfl_xor(s, 8);
                s += __shfl_xor(s, 4);  s += __shfl_xor(s, 2);  s += __shfl_xor(s, 1);
                if (lane == 0) st_f(&out[(bx << 9) + (it - 2)], bouts_s + s);
            }

            // gates2(it-1) += W2 . [h1(it-1); h2(it-2)]
            if (it >= 1) {
                const bool hi2 = (wv >= 4);
                const _Float16* bhB = hi2 ? HBUF(sR2, 1, 0) : HBUF(sR1, 0, 0);
                const _Float16* blB = hi2 ? HBUF(sR2, 1, 1) : HBUF(sR1, 0, 1);
                const int lo_off = ((wv & 3) << 12) + (lane << 3);
                #pragma unroll 1
                for (int bi = 0; bi < 16; ++bi) {
                    const int btl = (bi + (wv << 1)) & 15;
                    const _Float16* ph = bhB + (btl << 14) + lo_off;
                    const _Float16* pl = blB + (btl << 14) + lo_off;
                    half8 bh[8], bl[8];
                    #pragma unroll
                    for (int kt = 0; kt < 8; ++kt) {
                        bh[kt] = *(const half8*)(ph + (kt << 9));
                        bl[kt] = *(const half8*)(pl + (kt << 9));
                    }
                    f32x4 a0[2] = {(f32x4){0,0,0,0}, (f32x4){0,0,0,0}};
                    f32x4 a1[2] = {(f32x4){0,0,0,0}, (f32x4){0,0,0,0}};
                    #pragma unroll
                    for (int kt = 0; kt < 8; ++kt) {
                        MFMA_V(a0[0], wh[0][kt], bh[kt]);
                        MFMA_V(a1[0], wh[0][kt], bl[kt]);
                        MFMA_V(a1[0], wl[0][kt], bh[kt]);
                        MFMA_V(a0[1], wh[1][kt], bh[kt]);
                        MFMA_V(a1[1], wh[1][kt], bl[kt]);
                        MFMA_V(a1[1], wl[1][kt], bh[kt]);
                    }
                    const int col = (btl << 4) + m;
                    #pragma unroll
                    for (int mt = 0; mt < 2; ++mt)
                        #pragma unroll
                        for (int r = 0; r < 4; ++r)
                            atomicAdd(&gAcc[((mt << 4) + (quad << 2) + r) * GSTR + col],
                                      a0[mt][r] + a1[mt][r] * INV2048);
                }
            }

            __syncthreads();

            if (it >= 1) {             // layer-2 cell for t=it-1 -> h2(it-1) @slot sW2
                half4 hhi, hlo;
                float po = 0.0f;
                #pragma unroll
                for (int j = 0; j < 4; ++j) {
                    const int p = (hg << 4) + (j << 2);
                    const float gi = gAcc[(p + 0) * GSTR + b_ep];
                    const float gf = gAcc[(p + 1) * GSTR + b_ep];
                    const float gg = gAcc[(p + 2) * GSTR + b_ep];
                    const float go = gAcc[(p + 3) * GSTR + b_ep];
                    const float c  = sigm(gf) * cr[j] + sigm(gi) * tanh_f(gg);
                    cr[j] = c;
                    const float hn = sigm(go) * tanh_f(c);
                    hhi[j] = (_Float16)hn;
                    hlo[j] = (_Float16)((hn - (float)hhi[j]) * 2048.0f);
                    po += hn * woutp[(hg << 2) + j];
                }
                st_h4(HBUF(sW2, 1, 0) + wofs, hhi);
                st_h4(HBUF(sW2, 1, 1) + wofs, hlo);
                poArr[hg * GSTR + b_ep] = po;
                #pragma unroll
                for (int p = (hg << 4); p < (hg << 4) + 16; ++p)
                    gAcc[p * GSTR + b_ep] = bp[p];
            }
            __syncthreads();
            if (it >= 1 && tid < 256) {   // partials[sPW][b][rg]
                const float s = poArr[tid] + poArr[GSTR + tid];
                st_f(&partials[(sPW << 15) + (tid << 7) + rg], s);
            }

            step_barrier(arrX, flagX, bar1, dummyv, isLead, xcc, nLead, nBlkX,
                         (unsigned)(it + 1));
        }
    }

    // tail: out column t=511 (partials slot (512+1)&3 = 1, written at it=512)
    if (wv == 0) {
        const float* pp = partials + (1 << 15) + (bx << 7);
        float s = pp[lane] + pp[lane + 64];
        s += __shfl_xor(s, 32); s += __shfl_xor(s, 16); s += __shfl_xor(s, 8);
        s += __shfl_xor(s, 4);  s += __shfl_xor(s, 2);  s += __shfl_xor(s, 1);
        if (lane == 0) st_f(&out[(bx << 9) + (Tsz - 1)], bouts_s + s);
    }
    #undef HBUF
}

// ---------------------------------------------------------------------------
extern "C" void kernel_launch(void* const* d_in, const int* in_sizes, int n_in,
                              void* d_out, int out_size, void* d_ws, size_t ws_size,
                              hipStream_t stream)
{
    const float* x     = (const float*)d_in[0];
    const float* W_ih1 = (const float*)d_in[1];
    const float* W_hh1 = (const float*)d_in[2];
    const float* b_ih1 = (const float*)d_in[3];
    const float* b_hh1 = (const float*)d_in[4];
    const float* W_ih2 = (const float*)d_in[5];
    const float* W_hh2 = (const float*)d_in[6];
    const float* b_ih2 = (const float*)d_in[7];
    const float* b_hh2 = (const float*)d_in[8];
    const float* W_out = (const float*)d_in[9];
    const float* b_out = (const float*)d_in[10];
    float* out = (float*)d_out;
    char*  ws  = (char*)d_ws;

    void* args[] = {
        (void*)&x,
        (void*)&W_ih1, (void*)&W_hh1, (void*)&b_ih1, (void*)&b_hh1,
        (void*)&W_ih2, (void*)&W_hh2, (void*)&b_ih2, (void*)&b_hh2,
        (void*)&W_out, (void*)&b_out, (void*)&out, (void*)&ws,
    };
    hipLaunchCooperativeKernel((const void*)lstm_persist,
                               dim3(256), dim3(512), args, 0, stream);
}